// Round 8
// baseline (259.272 us; speedup 1.0000x reference)
//
#include <hip/hip_runtime.h>
#include <math.h>

// Problem constants (reference: x_l [16, 1, 1536, 1536] fp32, PATCH=3, ALPHA=1)
#define IMG_W 1536
#define IMG_H 1536
#define NIMG  16
#define RPB   8                     // output rows per block
#define NRW   (RPB + 2)             // staged rows incl. vertical halo
#define TCOLS 512                   // tile width (cols per block)
#define LROW  520                   // LDS row stride in floats (4 pad + 512 + halo)

typedef float f32x4 __attribute__((ext_vector_type(4)));

// out(h,w) = sum_k v_k*exp(-v_k) / sum_k exp(-v_k) over the 3x3 zero-padded
// neighborhood (the "-x^2" shift cancels in softmax; padded taps: e=1, ve=0).
//
// R12 change vs R11: THEORY 4. Across R0-R11 duration pinned at ~90-99us while
// fetch (74-240MB), VALU (25-50us), occupancy (29-82%) each varied 2-3x; no
// throughput resource is >40% used. The only consistent model: the per-CU
// outstanding-read-miss budget (MSHR/line tracking on the VGPR load path) caps
// reads at ~2.5-3.2 TB/s chip-wide (Little's law: ~32-64 x 64B lines/CU x
// ~400-700cy). Writes ride free (memset 6.6 TB/s); the "6.3 TB/s achievable"
// copy is ~3.15 TB/s of reads. The one read path proven to exceed this is
// global_load_lds (m97 GEMM stages >10 TB/s aggregate, no VGPR landing, deep
// queue). So: stage a 512x10 tile into LDS via DMA, compute 8 output rows from
// LDS with a rolling 3-row ring. Bonus: read amp 1.5->1.25, exp/px 2.25->1.875,
// the 12 scalar halo global-loads/wave disappear. XCD decode + plain stores kept.
__global__ __launch_bounds__(128, 4)
void WeightedAverage_55551107006568_kernel(const float* __restrict__ x,
                                           float* __restrict__ out) {
    __shared__ float lds[NRW][LROW];

    // ---- XCD-aware decode (3 xb * 192 yb * 16 img = 9216 blocks) ----
    const int bid   = blockIdx.x;
    const int xcd   = bid & 7;
    const int chunk = bid >> 3;                  // 0..1151 within this XCD
    const int z     = (xcd << 1) + (chunk / 576);    // 2 images per XCD
    const int rem   = chunk % 576;               // 192 yb * 3 xb
    const int yb    = rem / 3;
    const int xb    = rem - yb * 3;
    const int h0    = yb * RPB;                  // first output row
    const int c0blk = xb * TCOLS;                // block's first column

    const int tid  = threadIdx.x;
    const int lane = tid & 63;
    const int wid  = tid >> 6;                   // wave id (0/1), wave-uniform
    const size_t plane = (size_t)z * ((size_t)IMG_H * IMG_W);
    const float* xp = x + plane;
    float* op = out + plane;

    // ---- stage NRW rows into LDS via global_load_lds (16B per lane) ----
    // LDS dest is wave-uniform base + lane*16 (m104); our layout is exactly
    // linear per wave: lane l covers cols 4l..4l+3 of the wave's half-row.
#pragma unroll
    for (int i = 0; i < NRW; ++i) {
        int r = h0 - 1 + i;                      // block-uniform row
        r = r < 0 ? 0 : (r >= IMG_H ? IMG_H - 1 : r);  // clamp; zero-sel later
        const float* gp = xp + (size_t)r * IMG_W + c0blk + tid * 4; // per-lane
        float* lp = &lds[i][4] + wid * 256;      // wave-uniform LDS base
        __builtin_amdgcn_global_load_lds(
            (const __attribute__((address_space(1))) void*)gp,
            (__attribute__((address_space(3))) void*)lp, 16, 0, 0);
    }
    // ---- horizontal halo columns (2 per row), by 20 threads in parallel ----
    if (tid < NRW) {                             // left halos: rows 0..9
        const int i = tid;
        int r = h0 - 1 + i;
        r = r < 0 ? 0 : (r >= IMG_H ? IMG_H - 1 : r);
        float v = 0.f;                           // pad: x=0 -> e=1, ve=0
        if (xb > 0) v = xp[(size_t)r * IMG_W + c0blk - 1];
        lds[i][3] = v;
    } else if (tid >= 32 && tid < 32 + NRW) {    // right halos: rows 0..9
        const int i = tid - 32;
        int r = h0 - 1 + i;
        r = r < 0 ? 0 : (r >= IMG_H ? IMG_H - 1 : r);
        float v = 0.f;
        if (xb < 2) v = xp[(size_t)r * IMG_W + c0blk + TCOLS];
        lds[i][LROW - 4] = v;                    // float index 516
    }
    __syncthreads();                             // drains DMA (vmcnt) + ds_writes

    // ---- compute: rolling 3-row ring over the LDS tile ----
    const int cL = 4 + tid * 4;                  // own first col (LDS float idx)
    float hE[3][4], hVE[3][4];
#pragma unroll
    for (int i = 0; i < NRW; ++i) {
        const int r  = h0 - 1 + i;
        const bool rv = (r >= 0) && (r < IMG_H); // block-uniform
        const int s = i % 3;

        f32x4 mm = *(const f32x4*)&lds[i][cL];   // ds_read_b128
        float xl = 0.f, xr = 0.f;                // only edge lanes consume
        if (lane == 0)  xl = lds[i][cL - 1];     // wave-left neighbor / halo
        if (lane == 63) xr = lds[i][cL + 4];     // wave-right neighbor / halo
        if (!rv) { mm = (f32x4){0.f,0.f,0.f,0.f}; xl = 0.f; xr = 0.f; }

        const float e0 = __expf(-mm.x), v0 = mm.x * e0;
        const float e1 = __expf(-mm.y), v1 = mm.y * e1;
        const float e2 = __expf(-mm.z), v2 = mm.z * e2;
        const float e3 = __expf(-mm.w), v3 = mm.w * e3;
        const float el = __expf(-xl),   vl = xl * el;   // edge-lane halo e/v
        const float er = __expf(-xr),   vr = xr * er;
        // interior lanes: neighbor's boundary column via shfl (computed once there)
        const float e3s = __shfl_up(e3, 1),   v3s = __shfl_up(v3, 1);
        const float e0s = __shfl_down(e0, 1), v0s = __shfl_down(v0, 1);
        const float eL = (lane == 0)  ? el : e3s;
        const float vL = (lane == 0)  ? vl : v3s;
        const float eR = (lane == 63) ? er : e0s;
        const float vR = (lane == 63) ? vr : v0s;

        hE[s][0] = eL + e0 + e1;  hVE[s][0] = vL + v0 + v1;
        hE[s][1] = e0 + e1 + e2;  hVE[s][1] = v0 + v1 + v2;
        hE[s][2] = e1 + e2 + e3;  hVE[s][2] = v1 + v2 + v3;
        hE[s][3] = e2 + e3 + eR;  hVE[s][3] = v2 + v3 + vR;

        if (i >= 2) {
            const int ro = h0 + i - 2;           // output row
            f32x4 o;
#pragma unroll
            for (int p = 0; p < 4; ++p) {
                const float den = hE[0][p] + hE[1][p] + hE[2][p];
                const float num = hVE[0][p] + hVE[1][p] + hVE[2][p];
                o[p] = __fdividef(num, den);
            }
            *(f32x4*)(op + (size_t)ro * IMG_W + c0blk + tid * 4) = o;
        }
    }
}

extern "C" void kernel_launch(void* const* d_in, const int* in_sizes, int n_in,
                              void* d_out, int out_size, void* d_ws, size_t ws_size,
                              hipStream_t stream) {
    const float* x = (const float*)d_in[0];
    float* out = (float*)d_out;
    // flat grid: 3 xb * 192 yb * 16 img = 9216 blocks, decoded in-kernel
    dim3 grid(9216, 1, 1);
    dim3 block(128, 1, 1);
    WeightedAverage_55551107006568_kernel<<<grid, block, 0, stream>>>(x, out);
}